// Round 14
// baseline (234.857 us; speedup 1.0000x reference)
//
#include <hip/hip_runtime.h>
#include <hip/hip_bf16.h>
#include <math.h>

#define B 32
#define P 100
#define N 1000
#define D 128

constexpr float SQRT_D_INV = 1.0f / 11.313708498984761f;
constexpr float CLIPV = 10.0f;

__device__ __forceinline__ void fma4(float4& a, float s, const float4& b) {
    a.x = fmaf(s, b.x, a.x);
    a.y = fmaf(s, b.y, a.y);
    a.z = fmaf(s, b.z, a.z);
    a.w = fmaf(s, b.w, a.w);
}

#define GLDS(gsrc, ldst) __builtin_amdgcn_global_load_lds( \
    (const __attribute__((address_space(1))) void*)(gsrc), \
    (__attribute__((address_space(3))) void*)(ldst), 16, 0, 0)

// ---------------------------------------------------------------------------
// K0: prep = weight transposes (blocks 0..127) + nodes transpose (rest).
// ---------------------------------------------------------------------------
#define TT 64
__global__ __launch_bounds__(256) void prep_kernel(
        const float* __restrict__ nodes,
        const float* __restrict__ Wk,  const float* __restrict__ Wv,
        const float* __restrict__ Wqf, const float* __restrict__ Wql,
        float* __restrict__ wkT,  float* __restrict__ wvT,
        float* __restrict__ wqfT, float* __restrict__ wqlT,
        float* __restrict__ nodesT) {
    const int t = threadIdx.x;
    if (blockIdx.x < D) {
        const int e = blockIdx.x;
        const int d = t & 127;
        if ((t >> 7) == 0) {
            wkT[e * D + d] = Wk[d * D + e];
            wvT[e * D + d] = Wv[d * D + e];
        } else {
            wqfT[e * D + d] = Wqf[d * D + e];
            wqlT[e * D + d] = Wql[d * D + e];
        }
        return;
    }
    __shared__ float sh[TT][D + 1];
    const int blk = blockIdx.x - D;
    const int ntiles = (N + TT - 1) / TT;   // 16
    const int b  = blk / ntiles;
    const int n0 = (blk % ntiles) * TT;
    const int rows = min(TT, N - n0);

    const float4* src = (const float4*)(nodes + ((long)b * N + n0) * D);
    for (int i = t; i < rows * (D / 4); i += 256) {
        int r = i >> 5, c = i & 31;
        float4 v = src[(long)r * (D / 4) + c];
        sh[r][c * 4 + 0] = v.x; sh[r][c * 4 + 1] = v.y;
        sh[r][c * 4 + 2] = v.z; sh[r][c * 4 + 3] = v.w;
    }
    __syncthreads();

    const int nl = t & 63;
    const int eg = t >> 6;
    if (nl < rows) {
        #pragma unroll
        for (int k = 0; k < 32; ++k) {
            int e = eg * 32 + k;
            nodesT[((long)b * D + e) * N + n0 + nl] = sh[nl][e];
        }
    }
}

// ---------------------------------------------------------------------------
// K1: ek = exp(nodes @ WkT), ekv = ek * (nodes @ WvT).  (R20-proven: LDS
// weight staging via glds double-buffer; 8x less L2 weight traffic.)
// ---------------------------------------------------------------------------
#define R1 64
#define CH 8
__global__ __launch_bounds__(512) void kv_kernel(
        const float* __restrict__ nodes,
        const float* __restrict__ wkT,
        const float* __restrict__ wvT,
        float* __restrict__ ek,
        float* __restrict__ ekv) {
    __shared__ float sh[R1][D];
    __shared__ __align__(16) float wL[2][2][CH * D];
    const int t = threadIdx.x;
    const int lane = t & 63;
    const int wid = t >> 6;             // 0..7
    const int dq = t & 31;
    const int rl = t >> 5;              // 0..15, 4 rows each
    const long row0 = (long)blockIdx.x * R1;

    const float4* src = (const float4*)(nodes + row0 * D);
    float4* dst = (float4*)(&sh[0][0]);
    #pragma unroll
    for (int i = 0; i < (R1 * D / 4) / 512; ++i)
        dst[t + i * 512] = src[t + i * 512];

    // stage weight chunk 0 into buf 0: 8 waves x 1KB glds
    {
        const int seg = wid & 3;
        const float* g = (wid < 4 ? wkT : wvT) + seg * 256 + lane * 4;
        GLDS(g, &wL[0][wid < 4 ? 0 : 1][seg * 256]);
    }
    __syncthreads();                    // sh + chunk0 ready

    float4 ka[4], va[4];
    #pragma unroll
    for (int rr = 0; rr < 4; ++rr) {
        ka[rr] = make_float4(0.f, 0.f, 0.f, 0.f);
        va[rr] = make_float4(0.f, 0.f, 0.f, 0.f);
    }

    int buf = 0;
    for (int c = 0; c < D / CH; ++c) {
        if (c + 1 < D / CH) {
            const int seg = wid & 3;
            const float* g = (wid < 4 ? wkT : wvT)
                           + (long)(c + 1) * CH * D + seg * 256 + lane * 4;
            GLDS(g, &wL[buf ^ 1][wid < 4 ? 0 : 1][seg * 256]);
        }

        const float* wkb = &wL[buf][0][dq * 4];
        const float* wvb = &wL[buf][1][dq * 4];
        #pragma unroll
        for (int ee0 = 0; ee0 < CH; ee0 += 4) {
            float4 cwk[4], cwv[4];
            #pragma unroll
            for (int ee = 0; ee < 4; ++ee) {
                cwk[ee] = *(const float4*)(wkb + (ee0 + ee) * D);
                cwv[ee] = *(const float4*)(wvb + (ee0 + ee) * D);
            }
            const int e0 = c * CH + ee0;
            #pragma unroll
            for (int rr = 0; rr < 4; ++rr) {
                float4 s4 = *(const float4*)(&sh[rl * 4 + rr][e0]);
                fma4(ka[rr], s4.x, cwk[0]); fma4(ka[rr], s4.y, cwk[1]);
                fma4(ka[rr], s4.z, cwk[2]); fma4(ka[rr], s4.w, cwk[3]);
                fma4(va[rr], s4.x, cwv[0]); fma4(va[rr], s4.y, cwv[1]);
                fma4(va[rr], s4.z, cwv[2]); fma4(va[rr], s4.w, cwv[3]);
            }
        }
        __syncthreads();                // drains next-chunk glds; guards reuse
        buf ^= 1;
    }

    #pragma unroll
    for (int rr = 0; rr < 4; ++rr) {
        long row = row0 + rl * 4 + rr;
        float4 e4;
        e4.x = __expf(ka[rr].x); e4.y = __expf(ka[rr].y);
        e4.z = __expf(ka[rr].z); e4.w = __expf(ka[rr].w);
        float4 ev;
        ev.x = e4.x * va[rr].x; ev.y = e4.y * va[rr].y;
        ev.z = e4.z * va[rr].z; ev.w = e4.w * va[rr].w;
        *(float4*)(ek + row * D + dq * 4) = e4;
        *(float4*)(ekv + row * D + dq * 4) = ev;
    }
}

// ---------------------------------------------------------------------------
// K2: qsig = sigmoid(q1 @ Wqf^T + qlast @ Wql^T)  (R8-proven)
// ---------------------------------------------------------------------------
#define R2 16
__global__ __launch_bounds__(256) void q_kernel(
        const float* __restrict__ q1,
        const float* __restrict__ qlast,
        const float* __restrict__ wqfT,
        const float* __restrict__ wqlT,
        float* __restrict__ qsig) {
    __shared__ float sh1[R2][D];
    __shared__ float sh2[R2][D];
    const int t = threadIdx.x;
    const int dq = t & 31;
    const int rl = t >> 5;
    const long row0 = (long)blockIdx.x * R2;

    const float4* s1 = (const float4*)(q1 + row0 * D);
    const float4* s2 = (const float4*)(qlast + row0 * D);
    float4* d1 = (float4*)(&sh1[0][0]);
    float4* d2 = (float4*)(&sh2[0][0]);
    #pragma unroll
    for (int i = 0; i < (R2 * D / 4) / 256; ++i) {
        d1[t + i * 256] = s1[t + i * 256];
        d2[t + i * 256] = s2[t + i * 256];
    }
    __syncthreads();

    float4 acc[2];
    acc[0] = make_float4(0.f, 0.f, 0.f, 0.f);
    acc[1] = make_float4(0.f, 0.f, 0.f, 0.f);

    const float* wfp = wqfT + dq * 4;
    const float* wlp = wqlT + dq * 4;

    float4 cwf[4], cwl[4];
    #pragma unroll
    for (int ee = 0; ee < 4; ++ee) {
        cwf[ee] = *(const float4*)(wfp + ee * D);
        cwl[ee] = *(const float4*)(wlp + ee * D);
    }

    for (int e0 = 0; e0 < D; e0 += 4) {
        float4 nwf[4], nwl[4];
        if (e0 + 4 < D) {
            #pragma unroll
            for (int ee = 0; ee < 4; ++ee) {
                nwf[ee] = *(const float4*)(wfp + (e0 + 4 + ee) * D);
                nwl[ee] = *(const float4*)(wlp + (e0 + 4 + ee) * D);
            }
        }
        #pragma unroll
        for (int rr = 0; rr < 2; ++rr) {
            float4 a4 = *(const float4*)(&sh1[rl * 2 + rr][e0]);
            float4 b4 = *(const float4*)(&sh2[rl * 2 + rr][e0]);
            fma4(acc[rr], a4.x, cwf[0]); fma4(acc[rr], a4.y, cwf[1]);
            fma4(acc[rr], a4.z, cwf[2]); fma4(acc[rr], a4.w, cwf[3]);
            fma4(acc[rr], b4.x, cwl[0]); fma4(acc[rr], b4.y, cwl[1]);
            fma4(acc[rr], b4.z, cwl[2]); fma4(acc[rr], b4.w, cwl[3]);
        }
        #pragma unroll
        for (int ee = 0; ee < 4; ++ee) { cwf[ee] = nwf[ee]; cwl[ee] = nwl[ee]; }
    }

    #pragma unroll
    for (int rr = 0; rr < 2; ++rr) {
        long row = row0 + rl * 2 + rr;
        float4 s;
        s.x = 1.0f / (1.0f + __expf(-acc[rr].x));
        s.y = 1.0f / (1.0f + __expf(-acc[rr].y));
        s.z = 1.0f / (1.0f + __expf(-acc[rr].z));
        s.w = 1.0f / (1.0f + __expf(-acc[rr].w));
        *(float4*)(qsig + row * D + dq * 4) = s;
    }
}

// ---------------------------------------------------------------------------
// K3: partial num/den over an n-chunk.  (R17-proven body: PT3=50, NPT=2,
// 256 threads = 32 d-quads x 8 p-groups x 7 p's.)
// R23: XCD-pairing block swizzle.  Each ek/ekv slice (b,c) is read by
// exactly 2 blocks (pt=0,1).  Old b-fastest mapping put partners 512
// blockIdx apart AND gave each XCD 4 concurrent b's = 8MB > 4MB L2 ->
// both reads were L3 (~450-600cy), the exposed latency behind VALUBusy
// 33%.  New mapping (T1 model: XCD = blockIdx % 8):
//   phys = (g/8)*16 + pt*8 + (g&7),  g = c*B + b
// -> both pt-partners share phys%8 (same XCD) and are <=8 apart
// (temporally adjacent); per-XCD live working set ~4 slices x 64KB.
// Partner read becomes an L2 hit.  Logical indices unchanged ->
// bitwise-identical output.  Requires B*NC % 8 == 0 (B=32 ✓).
// ---------------------------------------------------------------------------
#define PT3 50
#define TS 32
#define EBC 57
__global__ __launch_bounds__(256) void aft_part_kernel(
        const float* __restrict__ cur_dist,
        const float* __restrict__ ninf,
        const float* __restrict__ ek,
        const float* __restrict__ ekv,
        const float* __restrict__ log_scale,
        const float* __restrict__ aft_alpha,
        float* __restrict__ pnum,
        float* __restrict__ pden,
        int NC, int L) {
    __shared__ float eb[2][TS][EBC];
    const int t = threadIdx.x;
    const int dq = t & 31;
    const int pg = t >> 5;                      // 0..7
    const int pbase = pg * 7;                   // 0..49 owned; 50..55 dead
    const int phys = blockIdx.x;
    const int g    = (phys >> 4) * 8 + (phys & 7);   // 0..B*NC-1
    const int pt   = (phys >> 3) & 1;                // partner pair on same XCD
    const int b    = g % B;
    const int c    = g / B;
    const int p0 = pt * PT3;
    const int n_begin = c * L;
    const int n_end = min(N, n_begin + L);
    const float lsA = log_scale[0] * aft_alpha[0];

    float4 num[7], den[7];
    #pragma unroll
    for (int i = 0; i < 7; ++i) {
        num[i] = make_float4(0.f, 0.f, 0.f, 0.f);
        den[i] = make_float4(0.f, 0.f, 0.f, 0.f);
    }

    float rv[7];
    int n0 = n_begin;
    int ts = min(TS, n_end - n0);

    #pragma unroll
    for (int k = 0; k < 7; ++k) {
        int s = t + k * 256;
        int pp = s >> 5, nl = s & 31;           // pp < 56
        rv[k] = 0.f;
        if (nl < ts && p0 + pp < P) {
            long idx = ((long)b * P + p0 + pp) * N + (n0 + nl);
            rv[k] = fmaf(-lsA, cur_dist[idx], ninf[idx]);
        }
    }

    int buf = 0;
    while (n0 < n_end) {
        #pragma unroll
        for (int k = 0; k < 7; ++k) {
            int s = t + k * 256;
            int pp = s >> 5, nl = s & 31;
            if (nl < ts) eb[buf][nl][pp] = __expf(rv[k]);
        }
        __syncthreads();

        const int n0n = n0 + ts;
        const int tsn = min(TS, n_end - n0n);
        if (n0n < n_end) {
            #pragma unroll
            for (int k = 0; k < 7; ++k) {
                int s = t + k * 256;
                int pp = s >> 5, nl = s & 31;
                rv[k] = 0.f;
                if (nl < tsn && p0 + pp < P) {
                    long idx = ((long)b * P + p0 + pp) * N + (n0n + nl);
                    rv[k] = fmaf(-lsA, cur_dist[idx], ninf[idx]);
                }
            }
        }

        const float* ekb = ek  + ((long)b * N + n0) * D + dq * 4;
        const float* evb = ekv + ((long)b * N + n0) * D + dq * 4;
        #pragma unroll 4
        for (int j = 0; j < ts; ++j) {
            float4 ekq = *(const float4*)(ekb + (long)j * D);
            float4 evq = *(const float4*)(evb + (long)j * D);
            float e0 = eb[buf][j][pbase + 0];
            float e1 = eb[buf][j][pbase + 1];
            float e2 = eb[buf][j][pbase + 2];
            float e3 = eb[buf][j][pbase + 3];
            float e4 = eb[buf][j][pbase + 4];
            float e5 = eb[buf][j][pbase + 5];
            float e6 = eb[buf][j][pbase + 6];
            fma4(num[0], e0, evq); fma4(den[0], e0, ekq);
            fma4(num[1], e1, evq); fma4(den[1], e1, ekq);
            fma4(num[2], e2, evq); fma4(den[2], e2, ekq);
            fma4(num[3], e3, evq); fma4(den[3], e3, ekq);
            fma4(num[4], e4, evq); fma4(den[4], e4, ekq);
            fma4(num[5], e5, evq); fma4(den[5], e5, ekq);
            fma4(num[6], e6, evq); fma4(den[6], e6, ekq);
        }
        buf ^= 1;
        n0 = n0n;
        ts = tsn;
    }

    #pragma unroll
    for (int r = 0; r < 7; ++r) {
        int pl_ = pbase + r;
        if (pl_ < PT3) {                        // drop the 6 dead rows
            int p = p0 + pl_;
            long o = (((long)c * B + b) * P + p) * D + dq * 4;
            *(float4*)(pnum + o) = num[r];
            *(float4*)(pden + o) = den[r];
        }
    }
}

// ---------------------------------------------------------------------------
// K3b: reduce chunks -> aft = qsig * num / den.  float4 + 2-chunk unroll.
// ---------------------------------------------------------------------------
__global__ __launch_bounds__(256) void aft_reduce_kernel(
        const float* __restrict__ pnum,
        const float* __restrict__ pden,
        const float* __restrict__ qsig,
        float* __restrict__ aft,
        int NC) {
    const long i = ((long)blockIdx.x * 256 + threadIdx.x) * 4;
    const long BPD = (long)B * P * D;
    float4 n = make_float4(0.f, 0.f, 0.f, 0.f);
    float4 d = make_float4(0.f, 0.f, 0.f, 0.f);
    int c = 0;
    for (; c + 2 <= NC; c += 2) {
        float4 a0 = *(const float4*)(pnum + (long)c * BPD + i);
        float4 a1 = *(const float4*)(pnum + (long)(c + 1) * BPD + i);
        float4 b0 = *(const float4*)(pden + (long)c * BPD + i);
        float4 b1 = *(const float4*)(pden + (long)(c + 1) * BPD + i);
        n.x += a0.x + a1.x; n.y += a0.y + a1.y;
        n.z += a0.z + a1.z; n.w += a0.w + a1.w;
        d.x += b0.x + b1.x; d.y += b0.y + b1.y;
        d.z += b0.z + b1.z; d.w += b0.w + b1.w;
    }
    if (c < NC) {
        float4 a0 = *(const float4*)(pnum + (long)c * BPD + i);
        float4 b0 = *(const float4*)(pden + (long)c * BPD + i);
        n.x += a0.x; n.y += a0.y; n.z += a0.z; n.w += a0.w;
        d.x += b0.x; d.y += b0.y; d.z += b0.z; d.w += b0.w;
    }
    float4 q = *(const float4*)(qsig + i);
    float4 o;
    o.x = q.x * n.x / d.x;
    o.y = q.y * n.y / d.y;
    o.z = q.z * n.z / d.z;
    o.w = q.w * n.w / d.w;
    *(float4*)(aft + i) = o;
}

// ---------------------------------------------------------------------------
// K4a: score_part — R20-proven shape (PT2=10, 128 threads, 2 n/thread).
// ---------------------------------------------------------------------------
#define PT2 10
#define SC 4
__global__ __launch_bounds__(128) void score_part_kernel(
        const float* __restrict__ aft,
        const float* __restrict__ nodesT,
        const float* __restrict__ cur_dist,
        const float* __restrict__ ninf,
        const float* __restrict__ log_scale,
        const float* __restrict__ dist_alpha,
        float* __restrict__ out,
        float* __restrict__ sums) {
    __shared__ float sa[PT2][D];
    __shared__ float red[2][PT2];
    const int t = threadIdx.x;
    const int wid = t >> 6;
    const int b    = blockIdx.x % B;
    const int rest = blockIdx.x / B;
    const int c    = rest % SC;
    const int pt   = rest / SC;
    const int p0 = pt * PT2;
    const float lsA = log_scale[0] * dist_alpha[0];

    // stage 10 aft rows (5 KB)
    for (int i = t; i < PT2 * D; i += 128) {
        sa[i >> 7][i & 127] = aft[((long)b * P + p0) * D + i];
    }
    __syncthreads();

    const int n0 = c * 256 + t * 2;
    const bool act = (n0 < N);
    const int ncl = act ? n0 : 0;
    const float* ntb = nodesT + (long)b * D * N;

    float2 acc[PT2];
    #pragma unroll
    for (int i = 0; i < PT2; ++i) acc[i] = make_float2(0.f, 0.f);

    float2 cx[4];
    #pragma unroll
    for (int ee = 0; ee < 4; ++ee)
        cx[ee] = *(const float2*)(ntb + (long)ee * N + ncl);

    for (int e0 = 0; e0 < D; e0 += 4) {
        float2 nx[4];
        if (e0 + 4 < D) {
            #pragma unroll
            for (int ee = 0; ee < 4; ++ee)
                nx[ee] = *(const float2*)(ntb + (long)(e0 + 4 + ee) * N + ncl);
        }
        #pragma unroll
        for (int i = 0; i < PT2; ++i) {
            float4 a4 = *(const float4*)(&sa[i][e0]);
            acc[i].x = fmaf(cx[0].x, a4.x, acc[i].x);
            acc[i].x = fmaf(cx[1].x, a4.y, acc[i].x);
            acc[i].x = fmaf(cx[2].x, a4.z, acc[i].x);
            acc[i].x = fmaf(cx[3].x, a4.w, acc[i].x);
            acc[i].y = fmaf(cx[0].y, a4.x, acc[i].y);
            acc[i].y = fmaf(cx[1].y, a4.y, acc[i].y);
            acc[i].y = fmaf(cx[2].y, a4.z, acc[i].y);
            acc[i].y = fmaf(cx[3].y, a4.w, acc[i].y);
        }
        #pragma unroll
        for (int ee = 0; ee < 4; ++ee) cx[ee] = nx[ee];
    }

    #pragma unroll
    for (int i = 0; i < PT2; ++i) {
        float2 ev = make_float2(0.f, 0.f);
        if (act) {
            long idx = ((long)b * P + p0 + i) * N + n0;
            float2 cd = *(const float2*)(cur_dist + idx);
            float2 nf = *(const float2*)(ninf + idx);
            float sx = fmaf(acc[i].x, SQRT_D_INV, -lsA * cd.x);
            float sy = fmaf(acc[i].y, SQRT_D_INV, -lsA * cd.y);
            float ax = fabsf(sx), ay = fabsf(sy);
            float rx = 1.f - 2.f / (__expf(2.f * ax) + 1.f);
            float ry = 1.f - 2.f / (__expf(2.f * ay) + 1.f);
            float scx = CLIPV * copysignf(rx, sx) + nf.x;
            float scy = CLIPV * copysignf(ry, sy) + nf.y;
            ev.x = __expf(scx);           // bounded: scx <= 10
            ev.y = __expf(scy);
            *(float2*)(out + idx) = ev;
        }
        // per-p partial denominator
        float s = ev.x + ev.y;
        #pragma unroll
        for (int o = 1; o < 64; o <<= 1) s += __shfl_xor(s, o, 64);
        if ((t & 63) == 0) red[wid][i] = s;
    }
    __syncthreads();
    if (t < PT2) {
        atomicAdd(&sums[b * P + p0 + t], red[0][t] + red[1][t]);
    }
}

// ---------------------------------------------------------------------------
// K4b: normalize — out[b,p,n] /= sums[b,p].  Block per (b,p) row.
// ---------------------------------------------------------------------------
__global__ __launch_bounds__(256) void normalize_kernel(
        float* __restrict__ out, const float* __restrict__ sums) {
    const int row = blockIdx.x;           // b*P + p
    const int t = threadIdx.x;
    const float inv = 1.0f / sums[row];
    float4* r = (float4*)(out + (long)row * N);
    if (t < N / 4) {
        float4 v = r[t];
        v.x *= inv; v.y *= inv; v.z *= inv; v.w *= inv;
        r[t] = v;
    }
}

// ---------------------------------------------------------------------------
extern "C" void kernel_launch(void* const* d_in, const int* in_sizes, int n_in,
                              void* d_out, int out_size, void* d_ws, size_t ws_size,
                              hipStream_t stream) {
    const float* nodes      = (const float*)d_in[0];
    const float* q1         = (const float*)d_in[1];
    const float* qlast      = (const float*)d_in[2];
    const float* cur_dist   = (const float*)d_in[3];
    const float* ninf       = (const float*)d_in[4];
    const float* log_scale  = (const float*)d_in[5];
    const float* Wqf        = (const float*)d_in[6];
    const float* Wql        = (const float*)d_in[7];
    const float* Wk         = (const float*)d_in[8];
    const float* Wv         = (const float*)d_in[9];
    const float* dist_alpha = (const float*)d_in[10];
    const float* aft_alpha  = (const float*)d_in[11];
    float* out = (float*)d_out;

    const long BND = (long)B * N * D;
    const long BPD = (long)B * P * D;
    const long W2  = (long)D * D;

    float* ws     = (float*)d_ws;
    float* ek     = ws;
    float* ekv    = ek + BND;
    float* qsig   = ekv + BND;
    float* aft    = qsig + BPD;
    float* wkT    = aft + BPD;
    float* wvT    = wkT + W2;
    float* wqfT   = wvT + W2;
    float* wqlT   = wqfT + W2;
    float* nodesT = wqlT + W2;
    float* sums   = nodesT + BND;        // B*P
    float* pnum   = sums + (long)B * P;

    long avail = (long)(ws_size / 4) - (3 * BND + 2 * BPD + 4 * W2 + (long)B * P);
    int NC = (int)(avail / (2 * BPD));
    if (NC < 1) NC = 1;
    if (NC > 16) NC = 16;
    int L = (N + NC - 1) / NC;
    NC = (N + L - 1) / L;
    float* pden = pnum + (long)NC * BPD;

    hipMemsetAsync(sums, 0, (size_t)B * P * sizeof(float), stream);
    prep_kernel<<<D + B * ((N + TT - 1) / TT), 256, 0, stream>>>(
        nodes, Wk, Wv, Wqf, Wql, wkT, wvT, wqfT, wqlT, nodesT);
    kv_kernel<<<(B * N) / R1, 512, 0, stream>>>(nodes, wkT, wvT, ek, ekv);
    q_kernel<<<(B * P) / R2, 256, 0, stream>>>(q1, qlast, wqfT, wqlT, qsig);
    aft_part_kernel<<<B * 2 * NC, 256, 0, stream>>>(
        cur_dist, ninf, ek, ekv, log_scale, aft_alpha, pnum, pden, NC, L);
    aft_reduce_kernel<<<(int)(BPD / 1024), 256, 0, stream>>>(pnum, pden, qsig, aft, NC);
    score_part_kernel<<<B * SC * (P / PT2), 128, 0, stream>>>(
        aft, nodesT, cur_dist, ninf, log_scale, dist_alpha, out, sums);
    normalize_kernel<<<B * P, 256, 0, stream>>>(out, sums);
}

// Round 15
// 232.853 us; speedup vs baseline: 1.0086x; 1.0086x over previous
//
#include <hip/hip_runtime.h>
#include <hip/hip_bf16.h>
#include <math.h>

#define B 32
#define P 100
#define N 1000
#define D 128

constexpr float SQRT_D_INV = 1.0f / 11.313708498984761f;
constexpr float CLIPV = 10.0f;

__device__ __forceinline__ void fma4(float4& a, float s, const float4& b) {
    a.x = fmaf(s, b.x, a.x);
    a.y = fmaf(s, b.y, a.y);
    a.z = fmaf(s, b.z, a.z);
    a.w = fmaf(s, b.w, a.w);
}

#define GLDS(gsrc, ldst) __builtin_amdgcn_global_load_lds( \
    (const __attribute__((address_space(1))) void*)(gsrc), \
    (__attribute__((address_space(3))) void*)(ldst), 16, 0, 0)

// ---------------------------------------------------------------------------
// K0: prep = weight transposes (blocks 0..127) + nodes transpose (rest).
// ---------------------------------------------------------------------------
#define TT 64
__global__ __launch_bounds__(256) void prep_kernel(
        const float* __restrict__ nodes,
        const float* __restrict__ Wk,  const float* __restrict__ Wv,
        const float* __restrict__ Wqf, const float* __restrict__ Wql,
        float* __restrict__ wkT,  float* __restrict__ wvT,
        float* __restrict__ wqfT, float* __restrict__ wqlT,
        float* __restrict__ nodesT) {
    const int t = threadIdx.x;
    if (blockIdx.x < D) {
        const int e = blockIdx.x;
        const int d = t & 127;
        if ((t >> 7) == 0) {
            wkT[e * D + d] = Wk[d * D + e];
            wvT[e * D + d] = Wv[d * D + e];
        } else {
            wqfT[e * D + d] = Wqf[d * D + e];
            wqlT[e * D + d] = Wql[d * D + e];
        }
        return;
    }
    __shared__ float sh[TT][D + 1];
    const int blk = blockIdx.x - D;
    const int ntiles = (N + TT - 1) / TT;   // 16
    const int b  = blk / ntiles;
    const int n0 = (blk % ntiles) * TT;
    const int rows = min(TT, N - n0);

    const float4* src = (const float4*)(nodes + ((long)b * N + n0) * D);
    for (int i = t; i < rows * (D / 4); i += 256) {
        int r = i >> 5, c = i & 31;
        float4 v = src[(long)r * (D / 4) + c];
        sh[r][c * 4 + 0] = v.x; sh[r][c * 4 + 1] = v.y;
        sh[r][c * 4 + 2] = v.z; sh[r][c * 4 + 3] = v.w;
    }
    __syncthreads();

    const int nl = t & 63;
    const int eg = t >> 6;
    if (nl < rows) {
        #pragma unroll
        for (int k = 0; k < 32; ++k) {
            int e = eg * 32 + k;
            nodesT[((long)b * D + e) * N + n0 + nl] = sh[nl][e];
        }
    }
}

// ---------------------------------------------------------------------------
// K1: ek = exp(nodes @ WkT), ekv = ek * (nodes @ WvT).  (R20-proven: LDS
// weight staging via glds double-buffer; 8x less L2 weight traffic.)
// ---------------------------------------------------------------------------
#define R1 64
#define CH 8
__global__ __launch_bounds__(512) void kv_kernel(
        const float* __restrict__ nodes,
        const float* __restrict__ wkT,
        const float* __restrict__ wvT,
        float* __restrict__ ek,
        float* __restrict__ ekv) {
    __shared__ float sh[R1][D];
    __shared__ __align__(16) float wL[2][2][CH * D];
    const int t = threadIdx.x;
    const int lane = t & 63;
    const int wid = t >> 6;             // 0..7
    const int dq = t & 31;
    const int rl = t >> 5;              // 0..15, 4 rows each
    const long row0 = (long)blockIdx.x * R1;

    const float4* src = (const float4*)(nodes + row0 * D);
    float4* dst = (float4*)(&sh[0][0]);
    #pragma unroll
    for (int i = 0; i < (R1 * D / 4) / 512; ++i)
        dst[t + i * 512] = src[t + i * 512];

    // stage weight chunk 0 into buf 0: 8 waves x 1KB glds
    {
        const int seg = wid & 3;
        const float* g = (wid < 4 ? wkT : wvT) + seg * 256 + lane * 4;
        GLDS(g, &wL[0][wid < 4 ? 0 : 1][seg * 256]);
    }
    __syncthreads();                    // sh + chunk0 ready

    float4 ka[4], va[4];
    #pragma unroll
    for (int rr = 0; rr < 4; ++rr) {
        ka[rr] = make_float4(0.f, 0.f, 0.f, 0.f);
        va[rr] = make_float4(0.f, 0.f, 0.f, 0.f);
    }

    int buf = 0;
    for (int c = 0; c < D / CH; ++c) {
        if (c + 1 < D / CH) {
            const int seg = wid & 3;
            const float* g = (wid < 4 ? wkT : wvT)
                           + (long)(c + 1) * CH * D + seg * 256 + lane * 4;
            GLDS(g, &wL[buf ^ 1][wid < 4 ? 0 : 1][seg * 256]);
        }

        const float* wkb = &wL[buf][0][dq * 4];
        const float* wvb = &wL[buf][1][dq * 4];
        #pragma unroll
        for (int ee0 = 0; ee0 < CH; ee0 += 4) {
            float4 cwk[4], cwv[4];
            #pragma unroll
            for (int ee = 0; ee < 4; ++ee) {
                cwk[ee] = *(const float4*)(wkb + (ee0 + ee) * D);
                cwv[ee] = *(const float4*)(wvb + (ee0 + ee) * D);
            }
            const int e0 = c * CH + ee0;
            #pragma unroll
            for (int rr = 0; rr < 4; ++rr) {
                float4 s4 = *(const float4*)(&sh[rl * 4 + rr][e0]);
                fma4(ka[rr], s4.x, cwk[0]); fma4(ka[rr], s4.y, cwk[1]);
                fma4(ka[rr], s4.z, cwk[2]); fma4(ka[rr], s4.w, cwk[3]);
                fma4(va[rr], s4.x, cwv[0]); fma4(va[rr], s4.y, cwv[1]);
                fma4(va[rr], s4.z, cwv[2]); fma4(va[rr], s4.w, cwv[3]);
            }
        }
        __syncthreads();                // drains next-chunk glds; guards reuse
        buf ^= 1;
    }

    #pragma unroll
    for (int rr = 0; rr < 4; ++rr) {
        long row = row0 + rl * 4 + rr;
        float4 e4;
        e4.x = __expf(ka[rr].x); e4.y = __expf(ka[rr].y);
        e4.z = __expf(ka[rr].z); e4.w = __expf(ka[rr].w);
        float4 ev;
        ev.x = e4.x * va[rr].x; ev.y = e4.y * va[rr].y;
        ev.z = e4.z * va[rr].z; ev.w = e4.w * va[rr].w;
        *(float4*)(ek + row * D + dq * 4) = e4;
        *(float4*)(ekv + row * D + dq * 4) = ev;
    }
}

// ---------------------------------------------------------------------------
// K2: qsig = sigmoid(q1 @ Wqf^T + qlast @ Wql^T)  (R8-proven)
// ---------------------------------------------------------------------------
#define R2 16
__global__ __launch_bounds__(256) void q_kernel(
        const float* __restrict__ q1,
        const float* __restrict__ qlast,
        const float* __restrict__ wqfT,
        const float* __restrict__ wqlT,
        float* __restrict__ qsig) {
    __shared__ float sh1[R2][D];
    __shared__ float sh2[R2][D];
    const int t = threadIdx.x;
    const int dq = t & 31;
    const int rl = t >> 5;
    const long row0 = (long)blockIdx.x * R2;

    const float4* s1 = (const float4*)(q1 + row0 * D);
    const float4* s2 = (const float4*)(qlast + row0 * D);
    float4* d1 = (float4*)(&sh1[0][0]);
    float4* d2 = (float4*)(&sh2[0][0]);
    #pragma unroll
    for (int i = 0; i < (R2 * D / 4) / 256; ++i) {
        d1[t + i * 256] = s1[t + i * 256];
        d2[t + i * 256] = s2[t + i * 256];
    }
    __syncthreads();

    float4 acc[2];
    acc[0] = make_float4(0.f, 0.f, 0.f, 0.f);
    acc[1] = make_float4(0.f, 0.f, 0.f, 0.f);

    const float* wfp = wqfT + dq * 4;
    const float* wlp = wqlT + dq * 4;

    float4 cwf[4], cwl[4];
    #pragma unroll
    for (int ee = 0; ee < 4; ++ee) {
        cwf[ee] = *(const float4*)(wfp + ee * D);
        cwl[ee] = *(const float4*)(wlp + ee * D);
    }

    for (int e0 = 0; e0 < D; e0 += 4) {
        float4 nwf[4], nwl[4];
        if (e0 + 4 < D) {
            #pragma unroll
            for (int ee = 0; ee < 4; ++ee) {
                nwf[ee] = *(const float4*)(wfp + (e0 + 4 + ee) * D);
                nwl[ee] = *(const float4*)(wlp + (e0 + 4 + ee) * D);
            }
        }
        #pragma unroll
        for (int rr = 0; rr < 2; ++rr) {
            float4 a4 = *(const float4*)(&sh1[rl * 2 + rr][e0]);
            float4 b4 = *(const float4*)(&sh2[rl * 2 + rr][e0]);
            fma4(acc[rr], a4.x, cwf[0]); fma4(acc[rr], a4.y, cwf[1]);
            fma4(acc[rr], a4.z, cwf[2]); fma4(acc[rr], a4.w, cwf[3]);
            fma4(acc[rr], b4.x, cwl[0]); fma4(acc[rr], b4.y, cwl[1]);
            fma4(acc[rr], b4.z, cwl[2]); fma4(acc[rr], b4.w, cwl[3]);
        }
        #pragma unroll
        for (int ee = 0; ee < 4; ++ee) { cwf[ee] = nwf[ee]; cwl[ee] = nwl[ee]; }
    }

    #pragma unroll
    for (int rr = 0; rr < 2; ++rr) {
        long row = row0 + rl * 2 + rr;
        float4 s;
        s.x = 1.0f / (1.0f + __expf(-acc[rr].x));
        s.y = 1.0f / (1.0f + __expf(-acc[rr].y));
        s.z = 1.0f / (1.0f + __expf(-acc[rr].z));
        s.w = 1.0f / (1.0f + __expf(-acc[rr].w));
        *(float4*)(qsig + row * D + dq * 4) = s;
    }
}

// ---------------------------------------------------------------------------
// K3: partial num/den over an n-chunk (PT3=50, NPT=2, 256 threads).
// R24: glds-staged ek/ekv.  R22/R23 pinned the stall: VGPR_Count=64 =
// 56 acc + EXACTLY one j's {ekq,evq} — the allocator left zero pipeline
// headroom, so each j serializes {issue 2 loads, ~700cy wait, 112cy FMA}
// (2.4 waves/SIMD x 112/812 = 33% = measured VALUBusy).  Register
// residency is unenforceable (R11/R19/R22); LDS residency is.  R12's
// identical staging was null only because THAT structure was bytes-bound
// (164MB -> 48us floor = its result); this one streams 66MB (19us floor)
// from 44us — real headroom.  Per 16-row tile: write eb -> barrier ->
// issue next tile's glds (zero VGPR) + rv prefetch -> compute 16 j's from
// LDS (ds_read_b128 ~120cy, broadcast across pg pairs) -> barrier (drains
// glds one full ~1800cy compute phase after issue).  Single eb buffer
// (safe: two barriers/tile), double ekL/evL: LDS 36.4KB -> 4 blocks/CU
// (= grid offer).  L rounded to x16 so all glds guards are wave-uniform;
// every ts is a multiple of 8 (1000 = 8x125).
// ---------------------------------------------------------------------------
#define PT3 50
#define TS3 16
#define EBC 57
__global__ __launch_bounds__(256) void aft_part_kernel(
        const float* __restrict__ cur_dist,
        const float* __restrict__ ninf,
        const float* __restrict__ ek,
        const float* __restrict__ ekv,
        const float* __restrict__ log_scale,
        const float* __restrict__ aft_alpha,
        float* __restrict__ pnum,
        float* __restrict__ pden,
        int NC, int L) {
    __shared__ float eb[TS3][EBC];                  // 3648 B
    __shared__ __align__(16) float ekL[2][TS3 * D]; // 16384 B
    __shared__ __align__(16) float evL[2][TS3 * D]; // 16384 B
    const int t = threadIdx.x;
    const int dq = t & 31;
    const int pg = t >> 5;                      // 0..7
    const int pbase = pg * 7;                   // 0..49 owned; 50..55 dead
    const int phys = blockIdx.x;
    const int g    = (phys >> 4) * 8 + (phys & 7);   // 0..B*NC-1
    const int pt   = (phys >> 3) & 1;                // partner pair on same XCD
    const int b    = g % B;
    const int c    = g / B;
    const int p0 = pt * PT3;
    const int n_begin = c * L;
    const int n_end = min(N, n_begin + L);
    const float lsA = log_scale[0] * aft_alpha[0];

    float4 num[7], den[7];
    #pragma unroll
    for (int i = 0; i < 7; ++i) {
        num[i] = make_float4(0.f, 0.f, 0.f, 0.f);
        den[i] = make_float4(0.f, 0.f, 0.f, 0.f);
    }

    const float* ekc = ek  + (long)b * N * D;
    const float* evc = ekv + (long)b * N * D;

    int n0 = n_begin;
    int ts = min(TS3, n_end - n0);

    // prologue: stage tile 0 into buf 0 (fire-and-forget) + rv(tile 0)
    {
        const float* gk = ekc + (long)n0 * D;
        const float* gv = evc + (long)n0 * D;
        for (int i = t; i < ts * 32; i += 256) {    // ts*32 mult of 256
            GLDS(gk + (long)i * 4, &ekL[0][i * 4]);
            GLDS(gv + (long)i * 4, &evL[0][i * 4]);
        }
    }
    float rv[4];
    #pragma unroll
    for (int k = 0; k < 4; ++k) {
        int s = t + k * 256;
        int pp = s >> 4, nl = s & 15;
        rv[k] = 0.f;
        if (pp < 56 && nl < ts && p0 + pp < P) {
            long idx = ((long)b * P + p0 + pp) * N + (n0 + nl);
            rv[k] = fmaf(-lsA, cur_dist[idx], ninf[idx]);
        }
    }

    int cur = 0;
    while (n0 < n_end) {
        // phase 1: materialize ebias tile
        #pragma unroll
        for (int k = 0; k < 4; ++k) {
            int s = t + k * 256;
            int pp = s >> 4, nl = s & 15;
            if (pp < 56 && nl < ts) eb[nl][pp] = __expf(rv[k]);
        }
        __syncthreads();    // publishes eb (also drains tile-0 glds on iter 0)

        // phase 2: issue next tile's staging + rv prefetch (no waits)
        const int n0n = n0 + ts;
        const int tsn = min(TS3, n_end - n0n);
        if (n0n < n_end) {
            const float* gk = ekc + (long)n0n * D;
            const float* gv = evc + (long)n0n * D;
            for (int i = t; i < tsn * 32; i += 256) {
                GLDS(gk + (long)i * 4, &ekL[cur ^ 1][i * 4]);
                GLDS(gv + (long)i * 4, &evL[cur ^ 1][i * 4]);
            }
            #pragma unroll
            for (int k = 0; k < 4; ++k) {
                int s = t + k * 256;
                int pp = s >> 4, nl = s & 15;
                rv[k] = 0.f;
                if (pp < 56 && nl < tsn && p0 + pp < P) {
                    long idx = ((long)b * P + p0 + pp) * N + (n0n + nl);
                    rv[k] = fmaf(-lsA, cur_dist[idx], ninf[idx]);
                }
            }
        }

        // phase 3: compute tile from LDS
        const float* ekp = &ekL[cur][dq * 4];
        const float* evp = &evL[cur][dq * 4];
        #pragma unroll 4
        for (int j = 0; j < ts; ++j) {
            float4 ekq = *(const float4*)(ekp + j * D);
            float4 evq = *(const float4*)(evp + j * D);
            float e0 = eb[j][pbase + 0];
            float e1 = eb[j][pbase + 1];
            float e2 = eb[j][pbase + 2];
            float e3 = eb[j][pbase + 3];
            float e4 = eb[j][pbase + 4];
            float e5 = eb[j][pbase + 5];
            float e6 = eb[j][pbase + 6];
            fma4(num[0], e0, evq); fma4(den[0], e0, ekq);
            fma4(num[1], e1, evq); fma4(den[1], e1, ekq);
            fma4(num[2], e2, evq); fma4(den[2], e2, ekq);
            fma4(num[3], e3, evq); fma4(den[3], e3, ekq);
            fma4(num[4], e4, evq); fma4(den[4], e4, ekq);
            fma4(num[5], e5, evq); fma4(den[5], e5, ekq);
            fma4(num[6], e6, evq); fma4(den[6], e6, ekq);
        }
        __syncthreads();    // drains next-tile glds; guards eb/ekL reuse
        cur ^= 1;
        n0 = n0n;
        ts = tsn;
    }

    #pragma unroll
    for (int r = 0; r < 7; ++r) {
        int pl_ = pbase + r;
        if (pl_ < PT3) {                        // drop the 6 dead rows
            int p = p0 + pl_;
            long o = (((long)c * B + b) * P + p) * D + dq * 4;
            *(float4*)(pnum + o) = num[r];
            *(float4*)(pden + o) = den[r];
        }
    }
}

// ---------------------------------------------------------------------------
// K3b: reduce chunks -> aft = qsig * num / den.  float4 + 2-chunk unroll.
// ---------------------------------------------------------------------------
__global__ __launch_bounds__(256) void aft_reduce_kernel(
        const float* __restrict__ pnum,
        const float* __restrict__ pden,
        const float* __restrict__ qsig,
        float* __restrict__ aft,
        int NC) {
    const long i = ((long)blockIdx.x * 256 + threadIdx.x) * 4;
    const long BPD = (long)B * P * D;
    float4 n = make_float4(0.f, 0.f, 0.f, 0.f);
    float4 d = make_float4(0.f, 0.f, 0.f, 0.f);
    int c = 0;
    for (; c + 2 <= NC; c += 2) {
        float4 a0 = *(const float4*)(pnum + (long)c * BPD + i);
        float4 a1 = *(const float4*)(pnum + (long)(c + 1) * BPD + i);
        float4 b0 = *(const float4*)(pden + (long)c * BPD + i);
        float4 b1 = *(const float4*)(pden + (long)(c + 1) * BPD + i);
        n.x += a0.x + a1.x; n.y += a0.y + a1.y;
        n.z += a0.z + a1.z; n.w += a0.w + a1.w;
        d.x += b0.x + b1.x; d.y += b0.y + b1.y;
        d.z += b0.z + b1.z; d.w += b0.w + b1.w;
    }
    if (c < NC) {
        float4 a0 = *(const float4*)(pnum + (long)c * BPD + i);
        float4 b0 = *(const float4*)(pden + (long)c * BPD + i);
        n.x += a0.x; n.y += a0.y; n.z += a0.z; n.w += a0.w;
        d.x += b0.x; d.y += b0.y; d.z += b0.z; d.w += b0.w;
    }
    float4 q = *(const float4*)(qsig + i);
    float4 o;
    o.x = q.x * n.x / d.x;
    o.y = q.y * n.y / d.y;
    o.z = q.z * n.z / d.z;
    o.w = q.w * n.w / d.w;
    *(float4*)(aft + i) = o;
}

// ---------------------------------------------------------------------------
// K4a: score_part — R20-proven shape (PT2=10, 128 threads, 2 n/thread).
// ---------------------------------------------------------------------------
#define PT2 10
#define SC 4
__global__ __launch_bounds__(128) void score_part_kernel(
        const float* __restrict__ aft,
        const float* __restrict__ nodesT,
        const float* __restrict__ cur_dist,
        const float* __restrict__ ninf,
        const float* __restrict__ log_scale,
        const float* __restrict__ dist_alpha,
        float* __restrict__ out,
        float* __restrict__ sums) {
    __shared__ float sa[PT2][D];
    __shared__ float red[2][PT2];
    const int t = threadIdx.x;
    const int wid = t >> 6;
    const int b    = blockIdx.x % B;
    const int rest = blockIdx.x / B;
    const int c    = rest % SC;
    const int pt   = rest / SC;
    const int p0 = pt * PT2;
    const float lsA = log_scale[0] * dist_alpha[0];

    // stage 10 aft rows (5 KB)
    for (int i = t; i < PT2 * D; i += 128) {
        sa[i >> 7][i & 127] = aft[((long)b * P + p0) * D + i];
    }
    __syncthreads();

    const int n0 = c * 256 + t * 2;
    const bool act = (n0 < N);
    const int ncl = act ? n0 : 0;
    const float* ntb = nodesT + (long)b * D * N;

    float2 acc[PT2];
    #pragma unroll
    for (int i = 0; i < PT2; ++i) acc[i] = make_float2(0.f, 0.f);

    float2 cx[4];
    #pragma unroll
    for (int ee = 0; ee < 4; ++ee)
        cx[ee] = *(const float2*)(ntb + (long)ee * N + ncl);

    for (int e0 = 0; e0 < D; e0 += 4) {
        float2 nx[4];
        if (e0 + 4 < D) {
            #pragma unroll
            for (int ee = 0; ee < 4; ++ee)
                nx[ee] = *(const float2*)(ntb + (long)(e0 + 4 + ee) * N + ncl);
        }
        #pragma unroll
        for (int i = 0; i < PT2; ++i) {
            float4 a4 = *(const float4*)(&sa[i][e0]);
            acc[i].x = fmaf(cx[0].x, a4.x, acc[i].x);
            acc[i].x = fmaf(cx[1].x, a4.y, acc[i].x);
            acc[i].x = fmaf(cx[2].x, a4.z, acc[i].x);
            acc[i].x = fmaf(cx[3].x, a4.w, acc[i].x);
            acc[i].y = fmaf(cx[0].y, a4.x, acc[i].y);
            acc[i].y = fmaf(cx[1].y, a4.y, acc[i].y);
            acc[i].y = fmaf(cx[2].y, a4.z, acc[i].y);
            acc[i].y = fmaf(cx[3].y, a4.w, acc[i].y);
        }
        #pragma unroll
        for (int ee = 0; ee < 4; ++ee) cx[ee] = nx[ee];
    }

    #pragma unroll
    for (int i = 0; i < PT2; ++i) {
        float2 ev = make_float2(0.f, 0.f);
        if (act) {
            long idx = ((long)b * P + p0 + i) * N + n0;
            float2 cd = *(const float2*)(cur_dist + idx);
            float2 nf = *(const float2*)(ninf + idx);
            float sx = fmaf(acc[i].x, SQRT_D_INV, -lsA * cd.x);
            float sy = fmaf(acc[i].y, SQRT_D_INV, -lsA * cd.y);
            float ax = fabsf(sx), ay = fabsf(sy);
            float rx = 1.f - 2.f / (__expf(2.f * ax) + 1.f);
            float ry = 1.f - 2.f / (__expf(2.f * ay) + 1.f);
            float scx = CLIPV * copysignf(rx, sx) + nf.x;
            float scy = CLIPV * copysignf(ry, sy) + nf.y;
            ev.x = __expf(scx);           // bounded: scx <= 10
            ev.y = __expf(scy);
            *(float2*)(out + idx) = ev;
        }
        // per-p partial denominator
        float s = ev.x + ev.y;
        #pragma unroll
        for (int o = 1; o < 64; o <<= 1) s += __shfl_xor(s, o, 64);
        if ((t & 63) == 0) red[wid][i] = s;
    }
    __syncthreads();
    if (t < PT2) {
        atomicAdd(&sums[b * P + p0 + t], red[0][t] + red[1][t]);
    }
}

// ---------------------------------------------------------------------------
// K4b: normalize — out[b,p,n] /= sums[b,p].  Block per (b,p) row.
// ---------------------------------------------------------------------------
__global__ __launch_bounds__(256) void normalize_kernel(
        float* __restrict__ out, const float* __restrict__ sums) {
    const int row = blockIdx.x;           // b*P + p
    const int t = threadIdx.x;
    const float inv = 1.0f / sums[row];
    float4* r = (float4*)(out + (long)row * N);
    if (t < N / 4) {
        float4 v = r[t];
        v.x *= inv; v.y *= inv; v.z *= inv; v.w *= inv;
        r[t] = v;
    }
}

// ---------------------------------------------------------------------------
extern "C" void kernel_launch(void* const* d_in, const int* in_sizes, int n_in,
                              void* d_out, int out_size, void* d_ws, size_t ws_size,
                              hipStream_t stream) {
    const float* nodes      = (const float*)d_in[0];
    const float* q1         = (const float*)d_in[1];
    const float* qlast      = (const float*)d_in[2];
    const float* cur_dist   = (const float*)d_in[3];
    const float* ninf       = (const float*)d_in[4];
    const float* log_scale  = (const float*)d_in[5];
    const float* Wqf        = (const float*)d_in[6];
    const float* Wql        = (const float*)d_in[7];
    const float* Wk         = (const float*)d_in[8];
    const float* Wv         = (const float*)d_in[9];
    const float* dist_alpha = (const float*)d_in[10];
    const float* aft_alpha  = (const float*)d_in[11];
    float* out = (float*)d_out;

    const long BND = (long)B * N * D;
    const long BPD = (long)B * P * D;
    const long W2  = (long)D * D;

    float* ws     = (float*)d_ws;
    float* ek     = ws;
    float* ekv    = ek + BND;
    float* qsig   = ekv + BND;
    float* aft    = qsig + BPD;
    float* wkT    = aft + BPD;
    float* wvT    = wkT + W2;
    float* wqfT   = wvT + W2;
    float* wqlT   = wqfT + W2;
    float* nodesT = wqlT + W2;
    float* sums   = nodesT + BND;        // B*P
    float* pnum   = sums + (long)B * P;

    long avail = (long)(ws_size / 4) - (3 * BND + 2 * BPD + 4 * W2 + (long)B * P);
    int NC = (int)(avail / (2 * BPD));
    if (NC < 1) NC = 1;
    if (NC > 16) NC = 16;
    // L multiple of 16 so every aft_part tile ts is a multiple of 8
    // (1000 = 8*125) -> all glds guard boundaries are 256-thread-uniform.
    int L = (((N + NC - 1) / NC) + 15) & ~15;
    NC = (N + L - 1) / L;
    float* pden = pnum + (long)NC * BPD;

    hipMemsetAsync(sums, 0, (size_t)B * P * sizeof(float), stream);
    prep_kernel<<<D + B * ((N + TT - 1) / TT), 256, 0, stream>>>(
        nodes, Wk, Wv, Wqf, Wql, wkT, wvT, wqfT, wqlT, nodesT);
    kv_kernel<<<(B * N) / R1, 512, 0, stream>>>(nodes, wkT, wvT, ek, ekv);
    q_kernel<<<(B * P) / R2, 256, 0, stream>>>(q1, qlast, wqfT, wqlT, qsig);
    aft_part_kernel<<<B * 2 * NC, 256, 0, stream>>>(
        cur_dist, ninf, ek, ekv, log_scale, aft_alpha, pnum, pden, NC, L);
    aft_reduce_kernel<<<(int)(BPD / 1024), 256, 0, stream>>>(pnum, pden, qsig, aft, NC);
    score_part_kernel<<<B * SC * (P / PT2), 128, 0, stream>>>(
        aft, nodesT, cur_dist, ninf, log_scale, dist_alpha, out, sums);
    normalize_kernel<<<B * P, 256, 0, stream>>>(out, sums);
}